// Round 4
// baseline (4288.858 us; speedup 1.0000x reference)
//
#include <hip/hip_runtime.h>
#include <hip/hip_bf16.h>

// =====================================================================
// PC-RNN on MI355X.
//   Wq = Wo^T Wo (precomputed);  u_t = (b_o - x_t) @ Wo (parallel GEMM)
// Loop step:  th=tanh(h); h_prior=0.9h+0.1(th@Wr^T + c@Wc^T + b_r)
//             tp=tanh(h_prior); g=tp@Wq+u_t; e=0.1(1-tp^2)g; h=h_prior-e
//             c -= 0.1 e@Wc;  store tp (errors GEMM post-loop)
// Sharding: 32 row-groups x 8 members (64-state slice each); weights
// LDS-resident (~158KB -> 1 block/CU).
// R4: TAGGED-PACKET dataflow sync. Every exchanged 8B word is
// [bf16 lo | bf16 hi | 16b step tag | pad], stored/loaded with relaxed
// agent-scope atomics (R3-verified coherence-point semantics). Producers
// fire-and-forget; consumers retry until tags match. No flags, no
// vmcnt-drain barriers => ~1 one-way trip per exchange instead of ~3 RTT.
// Exchanges interlock each other for overwrite safety.
// Also: dc = e@Wc via 2 MFMAs (was 64-iter scalar dot); fast exp2 tanh.
// =====================================================================

#define TSEQ 512
#define NBAT 256
#define NOUT 256
#define NCAU 64
#define NST  512

typedef __attribute__((ext_vector_type(8))) short short8;
typedef __attribute__((ext_vector_type(4))) float floatx4;
typedef unsigned long long ull;

__device__ __forceinline__ unsigned short f2b(float f) {
    union { float f; unsigned u; } v; v.f = f;
    unsigned r = v.u + 0x7FFFu + ((v.u >> 16) & 1u);
    return (unsigned short)(r >> 16);
}
__device__ __forceinline__ float b2f(unsigned short s) {
    union { unsigned u; float f; } v; v.u = ((unsigned)s) << 16;
    return v.f;
}
__device__ __forceinline__ float fast_tanh(float x) {
    float xc = fminf(fmaxf(x, -15.f), 15.f);
    float e  = __builtin_amdgcn_exp2f(xc * 2.885390081777927f);  // e^{2x}
    return (e - 1.f) * __builtin_amdgcn_rcpf(e + 1.f);
}

#define ATOMIC_ST64(p, v) __hip_atomic_store((p), (v), __ATOMIC_RELAXED, __HIP_MEMORY_SCOPE_AGENT)
#define ATOMIC_LD64(p)    __hip_atomic_load((p), __ATOMIC_RELAXED, __HIP_MEMORY_SCOPE_AGENT)
#define TAG_OF(v)         ((unsigned)((v) >> 32) & 0xffffu)

// ---------------- ws layout (bytes) ----------------
#define SZ_UTP  ((size_t)TSEQ * NBAT * NST * 2)            // 134,217,728
#define OFF_UTP ((size_t)0)
#define OFF_WQ  (OFF_UTP + SZ_UTP)                         // 512*512*2
#define OFF_THX (OFF_WQ + (size_t)NST * NST * 2)           // [32][8r][256pk] x 8B
#define OFF_TPX (OFF_THX + (size_t)32 * 8 * 256 * 8)
#define OFF_DCX (OFF_TPX + (size_t)32 * 8 * 256 * 8)       // [32][8m][8r][32pk] x 8B
#define SZ_ZERO ((size_t)3 * 32 * 8 * 256 * 8)             // thx+tpx+dcx (tags!)

// ---------------- Wq = Wo^T Wo ----------------
__global__ __launch_bounds__(256) void wq_kernel(const float* __restrict__ w_o,
                                                 unsigned short* __restrict__ wqo) {
    int idx = blockIdx.x * 256 + threadIdx.x;
    int i = idx >> 9, j = idx & 511;
    float s = 0.f;
    for (int o = 0; o < NOUT; ++o)
        s += w_o[(size_t)o * NST + i] * w_o[(size_t)o * NST + j];
    wqo[idx] = f2b(s);
}

// ---------------- u_t = (b_o - x_t) @ Wo ----------------
__global__ __launch_bounds__(256) void u_gemm(const float* __restrict__ x,
                                              const float* __restrict__ w_o,
                                              const float* __restrict__ b_o,
                                              unsigned short* __restrict__ u) {
    __shared__ __align__(16) unsigned short As[64 * 72];
    __shared__ __align__(16) unsigned short Bs[64 * 72];
    const int m0 = blockIdx.x * 64, n0 = blockIdx.y * 64;
    const int tid = threadIdx.x;
    const int w = tid >> 6, l = tid & 63, lm = l & 15, lq = l >> 4;
    floatx4 acc[4] = { {0,0,0,0}, {0,0,0,0}, {0,0,0,0}, {0,0,0,0} };
    for (int k0 = 0; k0 < NOUT; k0 += 64) {
        __syncthreads();
        {
            int r = tid >> 2, kk = (tid & 3) * 16;
            const float* src = x + (size_t)(m0 + r) * NOUT + k0 + kk;
            #pragma unroll
            for (int i = 0; i < 16; ++i)
                As[r * 72 + kk + i] = f2b(b_o[k0 + kk + i] - src[i]);
        }
        {
            int kr = tid >> 2, nn = (tid & 3) * 16;
            const float* src = w_o + (size_t)(k0 + kr) * NST + n0 + nn;
            #pragma unroll
            for (int i = 0; i < 16; ++i)
                Bs[(nn + i) * 72 + kr] = f2b(src[i]);
        }
        __syncthreads();
        #pragma unroll
        for (int kt = 0; kt < 2; ++kt) {
            short8 a = *reinterpret_cast<const short8*>(&As[(w * 16 + lm) * 72 + kt * 32 + lq * 8]);
            #pragma unroll
            for (int nt = 0; nt < 4; ++nt) {
                short8 b = *reinterpret_cast<const short8*>(&Bs[(nt * 16 + lm) * 72 + kt * 32 + lq * 8]);
                acc[nt] = __builtin_amdgcn_mfma_f32_16x16x32_bf16(a, b, acc[nt], 0, 0, 0);
            }
        }
    }
    #pragma unroll
    for (int nt = 0; nt < 4; ++nt)
        #pragma unroll
        for (int q = 0; q < 4; ++q) {
            int row = m0 + w * 16 + lq * 4 + q, col = n0 + nt * 16 + lm;
            u[(size_t)row * NST + col] = f2b(acc[nt][q]);
        }
}

// ---------------- errors = tp@Wo^T + b_o - x ----------------
__global__ __launch_bounds__(256) void err_gemm(const unsigned short* __restrict__ tpA,
                                                const float* __restrict__ w_o,
                                                const float* __restrict__ b_o,
                                                const float* __restrict__ x,
                                                float* __restrict__ out) {
    __shared__ __align__(16) unsigned short As[64 * 72];
    __shared__ __align__(16) unsigned short Bs[64 * 72];
    const int m0 = blockIdx.x * 64, n0 = blockIdx.y * 64;
    const int tid = threadIdx.x;
    const int w = tid >> 6, l = tid & 63, lm = l & 15, lq = l >> 4;
    floatx4 acc[4] = { {0,0,0,0}, {0,0,0,0}, {0,0,0,0}, {0,0,0,0} };
    for (int k0 = 0; k0 < NST; k0 += 64) {
        __syncthreads();
        {
            int r = tid >> 2, kk = (tid & 3) * 16;
            const uint4* src = reinterpret_cast<const uint4*>(tpA + (size_t)(m0 + r) * NST + k0 + kk);
            uint4* dst = reinterpret_cast<uint4*>(&As[r * 72 + kk]);
            dst[0] = src[0]; dst[1] = src[1];
        }
        {
            int nr = tid >> 2, kk = (tid & 3) * 16;
            const float* src = w_o + (size_t)(n0 + nr) * NST + k0 + kk;
            #pragma unroll
            for (int i = 0; i < 16; ++i)
                Bs[nr * 72 + kk + i] = f2b(src[i]);
        }
        __syncthreads();
        #pragma unroll
        for (int kt = 0; kt < 2; ++kt) {
            short8 a = *reinterpret_cast<const short8*>(&As[(w * 16 + lm) * 72 + kt * 32 + lq * 8]);
            #pragma unroll
            for (int nt = 0; nt < 4; ++nt) {
                short8 b = *reinterpret_cast<const short8*>(&Bs[(nt * 16 + lm) * 72 + kt * 32 + lq * 8]);
                acc[nt] = __builtin_amdgcn_mfma_f32_16x16x32_bf16(a, b, acc[nt], 0, 0, 0);
            }
        }
    }
    #pragma unroll
    for (int nt = 0; nt < 4; ++nt)
        #pragma unroll
        for (int q = 0; q < 4; ++q) {
            int row = m0 + w * 16 + lq * 4 + q, col = n0 + nt * 16 + lm;
            out[(size_t)row * NOUT + col] = acc[nt][q] + b_o[col] - x[(size_t)row * NOUT + col];
        }
}

// ---------------- persistent sequential loop ----------------
__global__ __launch_bounds__(256, 1) void loop_kernel(
    const float* __restrict__ c_init, const float* __restrict__ h_init,
    const float* __restrict__ w_r, const float* __restrict__ b_r,
    const float* __restrict__ w_c,
    unsigned short* __restrict__ utp, const unsigned short* __restrict__ wq,
    ull* __restrict__ thxU, ull* __restrict__ tpxU, ull* __restrict__ dcxU) {
    __shared__ __align__(16) short wrF[32768];
    __shared__ __align__(16) short wqF[32768];
    __shared__ __align__(16) short wcF[4096];   // B-frag: n=state, k=cause (c@Wc^T)
    __shared__ __align__(16) short wcT[4096];   // B-frag: n=cause, k=state (e@Wc)
    __shared__ __align__(16) unsigned short stage[8 * 520];
    __shared__ __align__(16) unsigned short errB[8 * 72];
    __shared__ __align__(16) unsigned short cS[8 * 72];

    const int tid = threadIdx.x;
    const int bid = blockIdx.x;
    const int member = bid & 7;     // 64-state slice within group
    const int grp = bid >> 3;       // row-group [0,32): rows grp*8..grp*8+7
    const int rows0 = grp * 8;
    const int w = tid >> 6, l = tid & 63, lm = l & 15, lq = l >> 4;
    const int jloc = w * 16 + lm;
    const int jglob = member * 64 + jloc;
    const int row = tid >> 5, ch = tid & 31;   // gather mapping: 8 rows x 32 chunks

    unsigned* utpU32 = (unsigned*)utp;

    // ---- prologue: format weights into B-fragment layout in LDS ----
    for (int idx = tid; idx < 4096; idx += 256) {
        int lane = idx & 63, kt = (idx >> 6) & 15, nt = idx >> 10;
        int s = member * 64 + nt * 16 + (lane & 15);
        int k = kt * 32 + (lane >> 4) * 8;
        const float* src = w_r + (size_t)s * NST + k;
        short8 v;
        #pragma unroll
        for (int jj = 0; jj < 8; ++jj) v[jj] = (short)f2b(src[jj]);
        *reinterpret_cast<short8*>(&wrF[((nt * 16 + kt) * 64 + lane) * 8]) = v;
        short8 v2 = *reinterpret_cast<const short8*>(wq + (size_t)s * NST + k);
        *reinterpret_cast<short8*>(&wqF[((nt * 16 + kt) * 64 + lane) * 8]) = v2;
    }
    for (int idx = tid; idx < 512; idx += 256) {
        int lane = idx & 63, kt2 = (idx >> 6) & 1, wv = idx >> 7;
        // wcF: n=state j (local), k=cause
        int j = member * 64 + wv * 16 + (lane & 15);
        int k = kt2 * 32 + (lane >> 4) * 8;
        const float* src = w_c + (size_t)j * NCAU + k;
        short8 v;
        #pragma unroll
        for (int jj = 0; jj < 8; ++jj) v[jj] = (short)f2b(src[jj]);
        *reinterpret_cast<short8*>(&wcF[((wv * 2 + kt2) * 64 + lane) * 8]) = v;
        // wcT: n=cause, k=state j (local)
        int n = wv * 16 + (lane & 15);
        int kb = kt2 * 32 + (lane >> 4) * 8;
        short8 v2;
        #pragma unroll
        for (int jj = 0; jj < 8; ++jj)
            v2[jj] = (short)f2b(w_c[(size_t)(member * 64 + kb + jj) * NCAU + n]);
        *reinterpret_cast<short8*>(&wcT[((wv * 2 + kt2) * 64 + lane) * 8]) = v2;
    }

    const float br_l = b_r[jglob];
    float hP[4] = {0.f, 0.f, 0.f, 0.f};
    if (l < 32) {
        #pragma unroll
        for (int q = 0; q < 4; ++q)
            hP[q] = h_init[(size_t)(rows0 + lq * 4 + q) * NST + jglob];
    }
    float cM0 = c_init[(size_t)(rows0 + row) * NCAU + ch * 2];
    float cM1 = c_init[(size_t)(rows0 + row) * NCAU + ch * 2 + 1];

    // ---- publish th(0) with tag 1 (fire-and-forget) ----
    {
        unsigned pk[4];
        #pragma unroll
        for (int q = 0; q < 4; ++q) {
            unsigned m_ = f2b(fast_tanh(hP[q]));
            unsigned p_ = __shfl_xor(m_, 1);
            pk[q] = m_ | (p_ << 16);
        }
        if (l < 32 && !(l & 1)) {
            #pragma unroll
            for (int q = 0; q < 4; ++q)
                ATOMIC_ST64(thxU + (size_t)grp * 2048 + (lq * 4 + q) * 256 + (jglob >> 1),
                            (ull)pk[q] | ((ull)1u << 32));
        }
    }

    ull* thp = thxU + (size_t)grp * 2048 + row * 256 + ch * 8;
    ull* tpp = tpxU + (size_t)grp * 2048 + row * 256 + ch * 8;
    ull* dcp = dcxU + (size_t)grp * 2048 + row * 32 + ch;   // + m*256

    for (int s = 0; s < TSEQ; ++s) {
        // u prefetch (own slice; plain load, L2-cached from u_gemm)
        float uR[4] = {0.f, 0.f, 0.f, 0.f};
        if (l < 32) {
            #pragma unroll
            for (int q = 0; q < 4; ++q)
                uR[q] = b2f(utp[((size_t)(s * NBAT + rows0 + lq * 4 + q)) * NST + jglob]);
        }
        // ---- gather th (tag s+1) + dc (tag s), retry until fresh ----
        ull tv[8], dv[8];
        {
            const unsigned thTag = (unsigned)(s + 1), dcTag = (unsigned)s;
            for (;;) {
                #pragma unroll
                for (int i = 0; i < 8; ++i) tv[i] = ATOMIC_LD64(thp + i);
                #pragma unroll
                for (int m = 0; m < 8; ++m) dv[m] = ATOMIC_LD64(dcp + (size_t)m * 256);
                bool ok = true;
                #pragma unroll
                for (int i = 0; i < 8; ++i) ok &= (TAG_OF(tv[i]) == thTag);
                #pragma unroll
                for (int m = 0; m < 8; ++m) ok &= (TAG_OF(dv[m]) == dcTag);
                if (ok) break;
                __builtin_amdgcn_s_sleep(2);
            }
        }
        // c update from dc partials
        {
            float d0 = 0.f, d1 = 0.f;
            #pragma unroll
            for (int m = 0; m < 8; ++m) {
                d0 += b2f((unsigned short)(dv[m] & 0xffffu));
                d1 += b2f((unsigned short)((dv[m] >> 16) & 0xffffu));
            }
            cM0 -= 0.1f * d0; cM1 -= 0.1f * d1;
            cS[row * 72 + ch * 2] = f2b(cM0);
            cS[row * 72 + ch * 2 + 1] = f2b(cM1);
        }
        // stage th into LDS
        {
            unsigned* sd = reinterpret_cast<unsigned*>(&stage[row * 520]);
            #pragma unroll
            for (int i = 0; i < 8; ++i) sd[ch * 8 + i] = (unsigned)(tv[i] & 0xffffffffu);
        }
        __syncthreads();
        // ---- M1: h_prior slice = 0.9h + 0.1(th@Wr^T + c@Wc^T + b_r) ----
        floatx4 acc = {0.f, 0.f, 0.f, 0.f};
        #pragma unroll
        for (int kt = 0; kt < 16; ++kt) {
            short8 a = {0, 0, 0, 0, 0, 0, 0, 0};
            if (lm < 8) a = *reinterpret_cast<const short8*>(&stage[lm * 520 + kt * 32 + lq * 8]);
            short8 b = *reinterpret_cast<const short8*>(&wrF[((w * 16 + kt) * 64 + l) * 8]);
            acc = __builtin_amdgcn_mfma_f32_16x16x32_bf16(a, b, acc, 0, 0, 0);
        }
        #pragma unroll
        for (int kt = 0; kt < 2; ++kt) {
            short8 a = {0, 0, 0, 0, 0, 0, 0, 0};
            if (lm < 8) a = *reinterpret_cast<const short8*>(&cS[lm * 72 + kt * 32 + lq * 8]);
            short8 b = *reinterpret_cast<const short8*>(&wcF[((w * 2 + kt) * 64 + l) * 8]);
            acc = __builtin_amdgcn_mfma_f32_16x16x32_bf16(a, b, acc, 0, 0, 0);
        }
        float hPr[4], tp[4];
        #pragma unroll
        for (int q = 0; q < 4; ++q) {
            hPr[q] = 0.9f * hP[q] + 0.1f * (acc[q] + br_l);
            tp[q] = fast_tanh(hPr[q]);
        }
        // ---- publish tp (tag s+1) + plain utp write ----
        {
            unsigned pk[4];
            #pragma unroll
            for (int q = 0; q < 4; ++q) {
                unsigned m_ = f2b(tp[q]);
                unsigned p_ = __shfl_xor(m_, 1);
                pk[q] = m_ | (p_ << 16);
            }
            if (l < 32 && !(l & 1)) {
                #pragma unroll
                for (int q = 0; q < 4; ++q) {
                    int r = lq * 4 + q;
                    ATOMIC_ST64(tpxU + (size_t)grp * 2048 + r * 256 + (jglob >> 1),
                                (ull)pk[q] | ((ull)(unsigned)(s + 1) << 32));
                    utpU32[((size_t)(s * NBAT) + rows0 + r) * 256 + (jglob >> 1)] = pk[q];
                }
            }
        }
        __syncthreads();   // all waves done reading stage (M1)
        // ---- gather tp (tag s+1), retry ----
        {
            ull pv[8];
            const unsigned tpTag = (unsigned)(s + 1);
            for (;;) {
                #pragma unroll
                for (int i = 0; i < 8; ++i) pv[i] = ATOMIC_LD64(tpp + i);
                bool ok = true;
                #pragma unroll
                for (int i = 0; i < 8; ++i) ok &= (TAG_OF(pv[i]) == tpTag);
                if (ok) break;
                __builtin_amdgcn_s_sleep(2);
            }
            unsigned* sd = reinterpret_cast<unsigned*>(&stage[row * 520]);
            #pragma unroll
            for (int i = 0; i < 8; ++i) sd[ch * 8 + i] = (unsigned)(pv[i] & 0xffffffffu);
        }
        __syncthreads();
        // ---- M2: g slice = tp@Wq + u_t ----
        floatx4 ac2 = {0.f, 0.f, 0.f, 0.f};
        #pragma unroll
        for (int kt = 0; kt < 16; ++kt) {
            short8 a = {0, 0, 0, 0, 0, 0, 0, 0};
            if (lm < 8) a = *reinterpret_cast<const short8*>(&stage[lm * 520 + kt * 32 + lq * 8]);
            short8 b = *reinterpret_cast<const short8*>(&wqF[((w * 16 + kt) * 64 + l) * 8]);
            ac2 = __builtin_amdgcn_mfma_f32_16x16x32_bf16(a, b, ac2, 0, 0, 0);
        }
        float eH[4];
        #pragma unroll
        for (int q = 0; q < 4; ++q) {
            float g = ac2[q] + uR[q];
            eH[q] = 0.1f * (1.f - tp[q] * tp[q]) * g;
            hP[q] = hPr[q] - eH[q];
        }
        if (l < 32) {
            #pragma unroll
            for (int q = 0; q < 4; ++q) errB[(lq * 4 + q) * 72 + jloc] = f2b(eH[q]);
        }
        // ---- publish th(next) (tag s+2) — doesn't need errB sync ----
        {
            unsigned pk[4];
            #pragma unroll
            for (int q = 0; q < 4; ++q) {
                unsigned m_ = f2b(fast_tanh(hP[q]));
                unsigned p_ = __shfl_xor(m_, 1);
                pk[q] = m_ | (p_ << 16);
            }
            if (l < 32 && !(l & 1)) {
                #pragma unroll
                for (int q = 0; q < 4; ++q)
                    ATOMIC_ST64(thxU + (size_t)grp * 2048 + (lq * 4 + q) * 256 + (jglob >> 1),
                                (ull)pk[q] | ((ull)(unsigned)(s + 2) << 32));
            }
        }
        __syncthreads();   // errB complete (also fences stage reads of M2)
        // ---- dc slice = e_h @ Wc via 2 MFMAs; publish (tag s+1) ----
        {
            floatx4 dacc = {0.f, 0.f, 0.f, 0.f};
            #pragma unroll
            for (int kt = 0; kt < 2; ++kt) {
                short8 a = {0, 0, 0, 0, 0, 0, 0, 0};
                if (lm < 8) a = *reinterpret_cast<const short8*>(&errB[lm * 72 + kt * 32 + lq * 8]);
                short8 b = *reinterpret_cast<const short8*>(&wcT[((w * 2 + kt) * 64 + l) * 8]);
                dacc = __builtin_amdgcn_mfma_f32_16x16x32_bf16(a, b, dacc, 0, 0, 0);
            }
            // lane: cause = w*16+lm, rows = lq*4+q (real: l<32)
            unsigned pk[4];
            #pragma unroll
            for (int q = 0; q < 4; ++q) {
                unsigned m_ = f2b(dacc[q]);
                unsigned p_ = __shfl_xor(m_, 1);
                pk[q] = m_ | (p_ << 16);
            }
            if (l < 32 && !(l & 1)) {
                #pragma unroll
                for (int q = 0; q < 4; ++q) {
                    int r = lq * 4 + q, pkt = w * 8 + (lm >> 1);
                    ATOMIC_ST64(dcxU + (size_t)grp * 2048 + member * 256 + r * 32 + pkt,
                                (ull)pk[q] | ((ull)(unsigned)(s + 1) << 32));
                }
            }
        }
    }
}

extern "C" void kernel_launch(void* const* d_in, const int* in_sizes, int n_in,
                              void* d_out, int out_size, void* d_ws, size_t ws_size,
                              hipStream_t stream) {
    const float* x      = (const float*)d_in[0];
    const float* c_init = (const float*)d_in[1];
    const float* h_init = (const float*)d_in[2];
    const float* w_o    = (const float*)d_in[3];
    const float* b_o    = (const float*)d_in[4];
    const float* w_c    = (const float*)d_in[5];
    const float* w_r    = (const float*)d_in[6];
    const float* b_r    = (const float*)d_in[7];

    char* wsb = (char*)d_ws;
    unsigned short* utp = (unsigned short*)(wsb + OFF_UTP);
    unsigned short* wq  = (unsigned short*)(wsb + OFF_WQ);
    ull*            thx = (ull*)(wsb + OFF_THX);
    ull*            tpx = (ull*)(wsb + OFF_TPX);
    ull*            dcx = (ull*)(wsb + OFF_DCX);

    // zero tagged exchange buffers (tags must start at 0)
    hipMemsetAsync(wsb + OFF_THX, 0, SZ_ZERO, stream);

    wq_kernel<<<dim3((NST * NST) / 256), dim3(256), 0, stream>>>(w_o, wq);
    u_gemm<<<dim3((TSEQ * NBAT) / 64, NST / 64), dim3(256), 0, stream>>>(x, w_o, b_o, utp);

    void* args[] = { (void*)&c_init, (void*)&h_init, (void*)&w_r, (void*)&b_r,
                     (void*)&w_c, (void*)&utp, (void*)&wq, (void*)&thx,
                     (void*)&tpx, (void*)&dcx };
    hipLaunchCooperativeKernel((void*)loop_kernel, dim3(256), dim3(256), args, 0, stream);

    err_gemm<<<dim3((TSEQ * NBAT) / 64, NOUT / 64), dim3(256), 0, stream>>>(utp, w_o, b_o, x, (float*)d_out);
}